// Round 9
// baseline (38.386 us; speedup 1.0000x reference)
//
#include <hip/hip_runtime.h>
#include <cmath>

typedef __bf16 bf16x8 __attribute__((ext_vector_type(8)));
typedef float f32x4 __attribute__((ext_vector_type(4)));

#define HEADS 16   // B*nH
#define TT 64      // T
#define FDIM 8192  // H*W*C
#define NCHUNK 16  // K-split chunks
#define CHUNKF 512 // FDIM / NCHUNK
#define PART_BYTES ((size_t)NCHUNK * HEADS * TT * TT * 2)   // 2 MB bf16 partials

// ---------------- Kernel 1: partial S = Q K^T over one f-chunk (bf16 MFMA) --------------
// grid (NCHUNK, HEADS), block 256 (4 waves, 2x2 wave tiling). Proven R8 body, 16 k-steps.
__global__ __launch_bounds__(256) void qk_partial(const float* __restrict__ Q,
                                                  const float* __restrict__ Km,
                                                  __bf16* __restrict__ part) {
    const int chunk = blockIdx.x;
    const int h     = blockIdx.y;
    const int lane  = threadIdx.x & 63;
    const int w     = threadIdx.x >> 6;
    const int pr    = (w & 1) << 5;
    const int qr    = (w >> 1) << 5;
    const int r16   = lane & 15;
    const int g     = lane >> 4;
    const int kb    = chunk * CHUNKF + (g << 3);

    const float4* qp = (const float4*)(Q  + ((size_t)h * TT + pr + r16) * FDIM + kb);
    const float4* kp = (const float4*)(Km + ((size_t)h * TT + qr + r16) * FDIM + kb);

    f32x4 acc[2][2] = {{{0.f,0.f,0.f,0.f},{0.f,0.f,0.f,0.f}},
                       {{0.f,0.f,0.f,0.f},{0.f,0.f,0.f,0.f}}};

    #pragma unroll
    for (int ks = 0; ks < CHUNKF / 32; ++ks) {
        bf16x8 a[2], b[2];
        #pragma unroll
        for (int t = 0; t < 2; ++t) {
            const float4 x0 = qp[(size_t)t * 32768 + ks * 8];
            const float4 x1 = qp[(size_t)t * 32768 + ks * 8 + 1];
            a[t][0]=(__bf16)x0.x; a[t][1]=(__bf16)x0.y; a[t][2]=(__bf16)x0.z; a[t][3]=(__bf16)x0.w;
            a[t][4]=(__bf16)x1.x; a[t][5]=(__bf16)x1.y; a[t][6]=(__bf16)x1.z; a[t][7]=(__bf16)x1.w;
            const float4 y0 = kp[(size_t)t * 32768 + ks * 8];
            const float4 y1 = kp[(size_t)t * 32768 + ks * 8 + 1];
            b[t][0]=(__bf16)y0.x; b[t][1]=(__bf16)y0.y; b[t][2]=(__bf16)y0.z; b[t][3]=(__bf16)y0.w;
            b[t][4]=(__bf16)y1.x; b[t][5]=(__bf16)y1.y; b[t][6]=(__bf16)y1.z; b[t][7]=(__bf16)y1.w;
        }
        #pragma unroll
        for (int i = 0; i < 2; ++i)
            #pragma unroll
            for (int j = 0; j < 2; ++j)
                acc[i][j] = __builtin_amdgcn_mfma_f32_16x16x32_bf16(a[i], b[j], acc[i][j], 0, 0, 0);
    }

    __bf16* pp = part + ((size_t)chunk * HEADS + h) * (TT * TT);
    #pragma unroll
    for (int i = 0; i < 2; ++i)
        #pragma unroll
        for (int j = 0; j < 2; ++j)
            #pragma unroll
            for (int r = 0; r < 4; ++r)
                pp[(pr + (i << 4) + (g << 2) + r) * TT + (qr + (j << 4) + r16)] =
                    (__bf16)acc[i][j][r];
}

// ---------------- Kernel 2 (fused): reduce partials in-block -> LDS S -> MFMA -> out -----
// grid (64, HEADS), block 256 = 4 waves. Phase 1: each thread reduces 16 S-elements over
// NCHUNK chunks (dwordx4 loads, L2-resident), rounds to bf16 into padded LDS (stride 72).
// Phase 2: proven R8 MFMA body with A-fragments from LDS; 1/1024 folded into epilogue
// (exact: 1024 = 2^10, bf16 rounding is power-of-2 invariant).
__global__ __launch_bounds__(256) void sv_fused(const float* __restrict__ V,
                                                const __bf16* __restrict__ part,
                                                float* __restrict__ out,
                                                const float g_scale) {
    __shared__ __bf16 Slds[TT * 72];   // 9216 B, row-padded +8 to spread banks

    const int h    = blockIdx.y;
    const int tid  = threadIdx.x;
    const int lane = tid & 63;
    const int w    = tid >> 6;
    const int r16  = lane & 15;
    const int g    = lane >> 4;
    const int colbase = blockIdx.x * 128 + w * 32;

    // ---- Phase 1: reduce NCHUNK bf16 partial tiles for this head ----
    {
        const unsigned int* pu = (const unsigned int*)part;   // 2048 dwords per (c,h) tile
        float s[16];
        #pragma unroll
        for (int i = 0; i < 16; ++i) s[i] = 0.f;
        #pragma unroll
        for (int c = 0; c < NCHUNK; ++c) {
            const unsigned int* b = pu + ((size_t)c * HEADS + h) * 2048 + tid * 8;
            const uint4 u0 = *(const uint4*)(b);
            const uint4 u1 = *(const uint4*)(b + 4);
            const unsigned int uu[8] = {u0.x, u0.y, u0.z, u0.w, u1.x, u1.y, u1.z, u1.w};
            #pragma unroll
            for (int i = 0; i < 8; ++i) {
                s[2 * i]     += __uint_as_float(uu[i] << 16);
                s[2 * i + 1] += __uint_as_float(uu[i] & 0xffff0000u);
            }
        }
        // thread owns elements [tid*16, tid*16+16) = row tid/4, col (tid&3)*16
        bf16x8 h0, h1;
        #pragma unroll
        for (int i = 0; i < 8; ++i) { h0[i] = (__bf16)s[i]; h1[i] = (__bf16)s[i + 8]; }
        __bf16* dst = Slds + (tid >> 2) * 72 + (tid & 3) * 16;
        *(bf16x8*)(dst)     = h0;
        *(bf16x8*)(dst + 8) = h1;
    }
    __syncthreads();

    // ---- Phase 2: O = gauss/1024 * S V (MFMA, proven R8 body; A from LDS) ----
    bf16x8 a[4][2];
    #pragma unroll
    for (int pt = 0; pt < 4; ++pt)
        #pragma unroll
        for (int ks = 0; ks < 2; ++ks)
            a[pt][ks] = *(const bf16x8*)(Slds + (pt * 16 + r16) * 72 + ks * 32 + g * 8);

    const float* Vh = V + (size_t)h * TT * FDIM;
    f32x4 acc[4][2] = {};

    #pragma unroll
    for (int jt = 0; jt < 2; ++jt) {
        #pragma unroll
        for (int ks = 0; ks < 2; ++ks) {
            float vf[8];
            #pragma unroll
            for (int i = 0; i < 8; ++i)
                vf[i] = Vh[(size_t)(ks * 32 + g * 8 + i) * FDIM + colbase + jt * 16 + r16];
            bf16x8 b;
            #pragma unroll
            for (int i = 0; i < 8; ++i) b[i] = (__bf16)vf[i];
            #pragma unroll
            for (int pt = 0; pt < 4; ++pt)
                acc[pt][jt] = __builtin_amdgcn_mfma_f32_16x16x32_bf16(a[pt][ks], b, acc[pt][jt], 0, 0, 0);
        }
    }

    #pragma unroll
    for (int jt = 0; jt < 2; ++jt) {
        const int col = colbase + jt * 16 + r16;
        const int m   = col >> 3;
        const float dx = (float)(m >> 5) - 15.5f;
        const float dy = (float)(m & 31) - 15.5f;
        const float gg = expf(-(dx * dx + dy * dy) * 0.02f) * g_scale;
        #pragma unroll
        for (int pt = 0; pt < 4; ++pt)
            #pragma unroll
            for (int r = 0; r < 4; ++r) {
                const int p = pt * 16 + (g << 2) + r;
                __builtin_nontemporal_store(acc[pt][jt][r] * gg,
                    &out[(size_t)h * TT * FDIM + (size_t)p * FDIM + col]);
            }
    }
}

// ================= Fallback (ws too small): proven R8 3-kernel path ======================
__global__ __launch_bounds__(256) void reduce_sb(const unsigned int* __restrict__ partU,
                                                 __bf16* __restrict__ Sbf) {
    const int e = blockIdx.x * 256 + threadIdx.x;   // pair index, 32768 total
    float s0 = 0.f, s1 = 0.f;
    #pragma unroll
    for (int c = 0; c < NCHUNK; ++c) {
        const unsigned int u = partU[(size_t)c * 32768 + e];
        s0 += __uint_as_float(u << 16);
        s1 += __uint_as_float(u & 0xffff0000u);
    }
    Sbf[2 * e]     = (__bf16)(s0 * (1.0f / 1024.0f));
    Sbf[2 * e + 1] = (__bf16)(s1 * (1.0f / 1024.0f));
}

__global__ __launch_bounds__(256) void sv_mfma(const float* __restrict__ V,
                                               const __bf16* __restrict__ Sbf,
                                               float* __restrict__ out,
                                               const float g_norm) {
    const int h    = blockIdx.y;
    const int lane = threadIdx.x & 63;
    const int w    = threadIdx.x >> 6;
    const int r16  = lane & 15;
    const int g    = lane >> 4;
    const int colbase = blockIdx.x * 128 + w * 32;

    const __bf16* Sh = Sbf + h * (TT * TT);
    bf16x8 a[4][2];
    #pragma unroll
    for (int pt = 0; pt < 4; ++pt)
        #pragma unroll
        for (int ks = 0; ks < 2; ++ks)
            a[pt][ks] = *(const bf16x8*)(Sh + (pt * 16 + r16) * TT + ks * 32 + g * 8);

    const float* Vh = V + (size_t)h * TT * FDIM;
    f32x4 acc[4][2] = {};

    #pragma unroll
    for (int jt = 0; jt < 2; ++jt) {
        #pragma unroll
        for (int ks = 0; ks < 2; ++ks) {
            float vf[8];
            #pragma unroll
            for (int i = 0; i < 8; ++i)
                vf[i] = Vh[(size_t)(ks * 32 + g * 8 + i) * FDIM + colbase + jt * 16 + r16];
            bf16x8 b;
            #pragma unroll
            for (int i = 0; i < 8; ++i) b[i] = (__bf16)vf[i];
            #pragma unroll
            for (int pt = 0; pt < 4; ++pt)
                acc[pt][jt] = __builtin_amdgcn_mfma_f32_16x16x32_bf16(a[pt][ks], b, acc[pt][jt], 0, 0, 0);
        }
    }

    #pragma unroll
    for (int jt = 0; jt < 2; ++jt) {
        const int col = colbase + jt * 16 + r16;
        const int m   = col >> 3;
        const float dx = (float)(m >> 5) - 15.5f;
        const float dy = (float)(m & 31) - 15.5f;
        const float gg = expf(-(dx * dx + dy * dy) * 0.02f) * g_norm;
        #pragma unroll
        for (int pt = 0; pt < 4; ++pt)
            #pragma unroll
            for (int r = 0; r < 4; ++r) {
                const int p = pt * 16 + (g << 2) + r;
                __builtin_nontemporal_store(acc[pt][jt][r] * gg,
                    &out[(size_t)h * TT * FDIM + (size_t)p * FDIM + col]);
            }
    }
}

extern "C" void kernel_launch(void* const* d_in, const int* in_sizes, int n_in,
                              void* d_out, int out_size, void* d_ws, size_t ws_size,
                              hipStream_t stream) {
    const float* Q  = (const float*)d_in[0];
    const float* Km = (const float*)d_in[1];
    const float* V  = (const float*)d_in[2];
    float* out = (float*)d_out;

    // Host-side separable Gaussian normalizer (exact, deterministic):
    double sx = 0.0;
    for (int x = 0; x < 32; ++x) { const double d = (double)x - 15.5; sx += exp(-d * d / 50.0); }
    const float g_norm  = (float)(1.0 / (sx * sx));
    const float g_scale = g_norm * (1.0f / 1024.0f);

    if (ws_size >= PART_BYTES) {
        // Fused 2-dispatch path: partials in ws, reduce merged into the SV kernel.
        __bf16* part = (__bf16*)d_ws;
        qk_partial<<<dim3(NCHUNK, HEADS), 256, 0, stream>>>(Q, Km, part);
        sv_fused<<<dim3(FDIM / 128, HEADS), 256, 0, stream>>>(V, part, out, g_scale);
    } else {
        // Fallback: proven R8 3-dispatch path (partials in d_out, bf16 S in ws).
        __bf16* part = (__bf16*)d_out;
        __bf16* Sbf  = (__bf16*)d_ws;   // 128 KB
        qk_partial<<<dim3(NCHUNK, HEADS), 256, 0, stream>>>(Q, Km, part);
        reduce_sb<<<dim3(128), 256, 0, stream>>>((const unsigned int*)part, Sbf);
        sv_mfma<<<dim3(FDIM / 128, HEADS), 256, 0, stream>>>(V, Sbf, out, g_norm);
    }
}

// Round 10
// 38.299 us; speedup vs baseline: 1.0023x; 1.0023x over previous
//
#include <hip/hip_runtime.h>
#include <cmath>

typedef __bf16 bf16x8 __attribute__((ext_vector_type(8)));
typedef float f32x4 __attribute__((ext_vector_type(4)));

#define HEADS 16   // B*nH
#define TT 64      // T
#define FDIM 8192  // H*W*C
#define NCHUNK 64  // K-split chunks: 1024 blocks -> 4 waves/SIMD in k1 (latency hiding)
#define CHUNKF 128 // FDIM / NCHUNK

// ---------------- Kernel 1: partial S = Q K^T over one f-chunk (bf16 MFMA) --------------
// grid (NCHUNK, HEADS), block 256 (4 waves, 2x2 wave tiling). R8 body, 4 k-steps.
__global__ __launch_bounds__(256) void qk_partial(const float* __restrict__ Q,
                                                  const float* __restrict__ Km,
                                                  __bf16* __restrict__ part) {
    const int chunk = blockIdx.x;
    const int h     = blockIdx.y;
    const int lane  = threadIdx.x & 63;
    const int w     = threadIdx.x >> 6;
    const int pr    = (w & 1) << 5;
    const int qr    = (w >> 1) << 5;
    const int r16   = lane & 15;
    const int g     = lane >> 4;
    const int kb    = chunk * CHUNKF + (g << 3);

    const float4* qp = (const float4*)(Q  + ((size_t)h * TT + pr + r16) * FDIM + kb);
    const float4* kp = (const float4*)(Km + ((size_t)h * TT + qr + r16) * FDIM + kb);

    f32x4 acc[2][2] = {{{0.f,0.f,0.f,0.f},{0.f,0.f,0.f,0.f}},
                       {{0.f,0.f,0.f,0.f},{0.f,0.f,0.f,0.f}}};

    #pragma unroll
    for (int ks = 0; ks < CHUNKF / 32; ++ks) {
        bf16x8 a[2], b[2];
        #pragma unroll
        for (int t = 0; t < 2; ++t) {
            const float4 x0 = qp[(size_t)t * 32768 + ks * 8];
            const float4 x1 = qp[(size_t)t * 32768 + ks * 8 + 1];
            a[t][0]=(__bf16)x0.x; a[t][1]=(__bf16)x0.y; a[t][2]=(__bf16)x0.z; a[t][3]=(__bf16)x0.w;
            a[t][4]=(__bf16)x1.x; a[t][5]=(__bf16)x1.y; a[t][6]=(__bf16)x1.z; a[t][7]=(__bf16)x1.w;
            const float4 y0 = kp[(size_t)t * 32768 + ks * 8];
            const float4 y1 = kp[(size_t)t * 32768 + ks * 8 + 1];
            b[t][0]=(__bf16)y0.x; b[t][1]=(__bf16)y0.y; b[t][2]=(__bf16)y0.z; b[t][3]=(__bf16)y0.w;
            b[t][4]=(__bf16)y1.x; b[t][5]=(__bf16)y1.y; b[t][6]=(__bf16)y1.z; b[t][7]=(__bf16)y1.w;
        }
        #pragma unroll
        for (int i = 0; i < 2; ++i)
            #pragma unroll
            for (int j = 0; j < 2; ++j)
                acc[i][j] = __builtin_amdgcn_mfma_f32_16x16x32_bf16(a[i], b[j], acc[i][j], 0, 0, 0);
    }

    // part[chunk][h][p][q] in bf16
    __bf16* pp = part + ((size_t)chunk * HEADS + h) * (TT * TT);
    #pragma unroll
    for (int i = 0; i < 2; ++i)
        #pragma unroll
        for (int j = 0; j < 2; ++j)
            #pragma unroll
            for (int r = 0; r < 4; ++r)
                pp[(pr + (i << 4) + (g << 2) + r) * TT + (qr + (j << 4) + r16)] =
                    (__bf16)acc[i][j][r];
}

// ---------------- Kernel 2: reduce bf16 partials over chunks, scale, emit bf16 S --------
__global__ __launch_bounds__(256) void reduce_sb(const unsigned int* __restrict__ partU,
                                                 __bf16* __restrict__ Sbf) {
    const int e = blockIdx.x * 256 + threadIdx.x;   // pair index, 32768 total
    float s0 = 0.f, s1 = 0.f;
    #pragma unroll
    for (int c = 0; c < NCHUNK; ++c) {
        const unsigned int u = partU[(size_t)c * 32768 + e];
        s0 += __uint_as_float(u << 16);            // low bf16 -> f32
        s1 += __uint_as_float(u & 0xffff0000u);    // high bf16 -> f32
    }
    Sbf[2 * e]     = (__bf16)(s0 * (1.0f / 1024.0f));
    Sbf[2 * e + 1] = (__bf16)(s1 * (1.0f / 1024.0f));
}

// ---------------- Kernel 3: O[h][p][j] = gauss[j>>3] * sum_q S[h][p][q] * V[h][q][j] -----
// MFMA (proven R8 body) + non-temporal output stores.
__global__ __launch_bounds__(256) void sv_mfma(const float* __restrict__ V,
                                               const __bf16* __restrict__ Sbf,
                                               float* __restrict__ out,
                                               const float g_norm) {
    const int h    = blockIdx.y;
    const int lane = threadIdx.x & 63;
    const int w    = threadIdx.x >> 6;
    const int r16  = lane & 15;
    const int g    = lane >> 4;
    const int colbase = blockIdx.x * 128 + w * 32;

    const __bf16* Sh = Sbf + h * (TT * TT);
    bf16x8 a[4][2];
    #pragma unroll
    for (int pt = 0; pt < 4; ++pt)
        #pragma unroll
        for (int ks = 0; ks < 2; ++ks)
            a[pt][ks] = *(const bf16x8*)(Sh + (pt * 16 + r16) * TT + ks * 32 + g * 8);

    const float* Vh = V + (size_t)h * TT * FDIM;
    f32x4 acc[4][2] = {};

    #pragma unroll
    for (int jt = 0; jt < 2; ++jt) {
        #pragma unroll
        for (int ks = 0; ks < 2; ++ks) {
            float vf[8];
            #pragma unroll
            for (int i = 0; i < 8; ++i)
                vf[i] = Vh[(size_t)(ks * 32 + g * 8 + i) * FDIM + colbase + jt * 16 + r16];
            bf16x8 b;
            #pragma unroll
            for (int i = 0; i < 8; ++i) b[i] = (__bf16)vf[i];
            #pragma unroll
            for (int pt = 0; pt < 4; ++pt)
                acc[pt][jt] = __builtin_amdgcn_mfma_f32_16x16x32_bf16(a[pt][ks], b, acc[pt][jt], 0, 0, 0);
        }
    }

    #pragma unroll
    for (int jt = 0; jt < 2; ++jt) {
        const int col = colbase + jt * 16 + r16;
        const int m   = col >> 3;
        const float dx = (float)(m >> 5) - 15.5f;
        const float dy = (float)(m & 31) - 15.5f;
        const float gg = expf(-(dx * dx + dy * dy) * 0.02f) * g_norm;
        #pragma unroll
        for (int pt = 0; pt < 4; ++pt)
            #pragma unroll
            for (int r = 0; r < 4; ++r) {
                const int p = pt * 16 + (g << 2) + r;
                __builtin_nontemporal_store(acc[pt][jt][r] * gg,
                    &out[(size_t)h * TT * FDIM + (size_t)p * FDIM + col]);
            }
    }
}

extern "C" void kernel_launch(void* const* d_in, const int* in_sizes, int n_in,
                              void* d_out, int out_size, void* d_ws, size_t ws_size,
                              hipStream_t stream) {
    const float* Q  = (const float*)d_in[0];
    const float* Km = (const float*)d_in[1];
    const float* V  = (const float*)d_in[2];
    float* out = (float*)d_out;
    // Partials (4.2 MB bf16) live inside d_out (dead before k3 overwrites); bf16 S in ws.
    __bf16* part = (__bf16*)d_out;
    __bf16* Sbf  = (__bf16*)d_ws;   // 128 KB

    // Host-side separable Gaussian normalizer (exact, deterministic):
    double sx = 0.0;
    for (int x = 0; x < 32; ++x) { const double d = (double)x - 15.5; sx += exp(-d * d / 50.0); }
    const float g_norm = (float)(1.0 / (sx * sx));

    qk_partial<<<dim3(NCHUNK, HEADS), 256, 0, stream>>>(Q, Km, part);
    reduce_sb<<<dim3(128), 256, 0, stream>>>((const unsigned int*)part, Sbf);
    sv_mfma<<<dim3(FDIM / 128, HEADS), 256, 0, stream>>>(V, Sbf, out, g_norm);
}

// Round 11
// 36.872 us; speedup vs baseline: 1.0410x; 1.0387x over previous
//
#include <hip/hip_runtime.h>
#include <cmath>

typedef __bf16 bf16x8 __attribute__((ext_vector_type(8)));
typedef float f32x4 __attribute__((ext_vector_type(4)));

#define HEADS 16   // B*nH
#define TT 64      // T
#define FDIM 8192  // H*W*C
#define NCHUNK 32  // K-split chunks (best-measured config, R8)
#define CHUNKF 256 // FDIM / NCHUNK

// ---------------- Kernel 1: partial S = Q K^T over one f-chunk (bf16 MFMA) --------------
// grid (NCHUNK, HEADS), block 256 (4 waves, 2x2 wave tiling). Proven R8 body.
__global__ __launch_bounds__(256) void qk_partial(const float* __restrict__ Q,
                                                  const float* __restrict__ Km,
                                                  __bf16* __restrict__ part) {
    const int chunk = blockIdx.x;
    const int h     = blockIdx.y;
    const int lane  = threadIdx.x & 63;
    const int w     = threadIdx.x >> 6;
    const int pr    = (w & 1) << 5;
    const int qr    = (w >> 1) << 5;
    const int r16   = lane & 15;
    const int g     = lane >> 4;
    const int kb    = chunk * CHUNKF + (g << 3);

    const float4* qp = (const float4*)(Q  + ((size_t)h * TT + pr + r16) * FDIM + kb);
    const float4* kp = (const float4*)(Km + ((size_t)h * TT + qr + r16) * FDIM + kb);

    f32x4 acc[2][2] = {{{0.f,0.f,0.f,0.f},{0.f,0.f,0.f,0.f}},
                       {{0.f,0.f,0.f,0.f},{0.f,0.f,0.f,0.f}}};

    #pragma unroll
    for (int ks = 0; ks < CHUNKF / 32; ++ks) {
        bf16x8 a[2], b[2];
        #pragma unroll
        for (int t = 0; t < 2; ++t) {
            const float4 x0 = qp[(size_t)t * 32768 + ks * 8];
            const float4 x1 = qp[(size_t)t * 32768 + ks * 8 + 1];
            a[t][0]=(__bf16)x0.x; a[t][1]=(__bf16)x0.y; a[t][2]=(__bf16)x0.z; a[t][3]=(__bf16)x0.w;
            a[t][4]=(__bf16)x1.x; a[t][5]=(__bf16)x1.y; a[t][6]=(__bf16)x1.z; a[t][7]=(__bf16)x1.w;
            const float4 y0 = kp[(size_t)t * 32768 + ks * 8];
            const float4 y1 = kp[(size_t)t * 32768 + ks * 8 + 1];
            b[t][0]=(__bf16)y0.x; b[t][1]=(__bf16)y0.y; b[t][2]=(__bf16)y0.z; b[t][3]=(__bf16)y0.w;
            b[t][4]=(__bf16)y1.x; b[t][5]=(__bf16)y1.y; b[t][6]=(__bf16)y1.z; b[t][7]=(__bf16)y1.w;
        }
        #pragma unroll
        for (int i = 0; i < 2; ++i)
            #pragma unroll
            for (int j = 0; j < 2; ++j)
                acc[i][j] = __builtin_amdgcn_mfma_f32_16x16x32_bf16(a[i], b[j], acc[i][j], 0, 0, 0);
    }

    // part[chunk][h][p][q] in bf16
    __bf16* pp = part + ((size_t)chunk * HEADS + h) * (TT * TT);
    #pragma unroll
    for (int i = 0; i < 2; ++i)
        #pragma unroll
        for (int j = 0; j < 2; ++j)
            #pragma unroll
            for (int r = 0; r < 4; ++r)
                pp[(pr + (i << 4) + (g << 2) + r) * TT + (qr + (j << 4) + r16)] =
                    (__bf16)acc[i][j][r];
}

// ---------------- Kernel 2: reduce bf16 partials over chunks, scale, emit bf16 S --------
__global__ __launch_bounds__(256) void reduce_sb(const unsigned int* __restrict__ partU,
                                                 __bf16* __restrict__ Sbf) {
    const int e = blockIdx.x * 256 + threadIdx.x;   // pair index, 32768 total
    float s0 = 0.f, s1 = 0.f;
    #pragma unroll
    for (int c = 0; c < NCHUNK; ++c) {
        const unsigned int u = partU[(size_t)c * 32768 + e];
        s0 += __uint_as_float(u << 16);            // low bf16 -> f32
        s1 += __uint_as_float(u & 0xffff0000u);    // high bf16 -> f32
    }
    Sbf[2 * e]     = (__bf16)(s0 * (1.0f / 1024.0f));
    Sbf[2 * e + 1] = (__bf16)(s1 * (1.0f / 1024.0f));
}

// ---------------- Kernel 3: O[h][p][j] = gauss[j>>3] * sum_q S[h][p][q] * V[h][q][j] -----
// MFMA (proven R8 body) + non-temporal output stores.
__global__ __launch_bounds__(256) void sv_mfma(const float* __restrict__ V,
                                               const __bf16* __restrict__ Sbf,
                                               float* __restrict__ out,
                                               const float g_norm) {
    const int h    = blockIdx.y;
    const int lane = threadIdx.x & 63;
    const int w    = threadIdx.x >> 6;
    const int r16  = lane & 15;
    const int g    = lane >> 4;
    const int colbase = blockIdx.x * 128 + w * 32;

    const __bf16* Sh = Sbf + h * (TT * TT);
    bf16x8 a[4][2];
    #pragma unroll
    for (int pt = 0; pt < 4; ++pt)
        #pragma unroll
        for (int ks = 0; ks < 2; ++ks)
            a[pt][ks] = *(const bf16x8*)(Sh + (pt * 16 + r16) * TT + ks * 32 + g * 8);

    const float* Vh = V + (size_t)h * TT * FDIM;
    f32x4 acc[4][2] = {};

    #pragma unroll
    for (int jt = 0; jt < 2; ++jt) {
        #pragma unroll
        for (int ks = 0; ks < 2; ++ks) {
            float vf[8];
            #pragma unroll
            for (int i = 0; i < 8; ++i)
                vf[i] = Vh[(size_t)(ks * 32 + g * 8 + i) * FDIM + colbase + jt * 16 + r16];
            bf16x8 b;
            #pragma unroll
            for (int i = 0; i < 8; ++i) b[i] = (__bf16)vf[i];
            #pragma unroll
            for (int pt = 0; pt < 4; ++pt)
                acc[pt][jt] = __builtin_amdgcn_mfma_f32_16x16x32_bf16(a[pt][ks], b, acc[pt][jt], 0, 0, 0);
        }
    }

    #pragma unroll
    for (int jt = 0; jt < 2; ++jt) {
        const int col = colbase + jt * 16 + r16;
        const int m   = col >> 3;
        const float dx = (float)(m >> 5) - 15.5f;
        const float dy = (float)(m & 31) - 15.5f;
        const float gg = expf(-(dx * dx + dy * dy) * 0.02f) * g_norm;
        #pragma unroll
        for (int pt = 0; pt < 4; ++pt)
            #pragma unroll
            for (int r = 0; r < 4; ++r) {
                const int p = pt * 16 + (g << 2) + r;
                __builtin_nontemporal_store(acc[pt][jt][r] * gg,
                    &out[(size_t)h * TT * FDIM + (size_t)p * FDIM + col]);
            }
    }
}

extern "C" void kernel_launch(void* const* d_in, const int* in_sizes, int n_in,
                              void* d_out, int out_size, void* d_ws, size_t ws_size,
                              hipStream_t stream) {
    const float* Q  = (const float*)d_in[0];
    const float* Km = (const float*)d_in[1];
    const float* V  = (const float*)d_in[2];
    float* out = (float*)d_out;
    // Partials (4.2 MB bf16) live inside d_out (dead before k3 overwrites); bf16 S in ws.
    __bf16* part = (__bf16*)d_out;
    __bf16* Sbf  = (__bf16*)d_ws;   // 128 KB

    // Host-side separable Gaussian normalizer (exact, deterministic):
    double sx = 0.0;
    for (int x = 0; x < 32; ++x) { const double d = (double)x - 15.5; sx += exp(-d * d / 50.0); }
    const float g_norm = (float)(1.0 / (sx * sx));

    qk_partial<<<dim3(NCHUNK, HEADS), 256, 0, stream>>>(Q, Km, part);
    reduce_sb<<<dim3(128), 256, 0, stream>>>((const unsigned int*)part, Sbf);
    sv_mfma<<<dim3(FDIM / 128, HEADS), 256, 0, stream>>>(V, Sbf, out, g_norm);
}